// Round 12
// baseline (1861.233 us; speedup 1.0000x reference)
//
#include <hip/hip_runtime.h>
#include <cstdint>
#include <cstddef>

#define BN 64
#define TN 512
#define DN 256
#define UN 256
#define NC 768            // 3*UN, order: r | z | h
#define SLOTS (TN + 5)    // slots TN..TN+3 = initial states, TN+4 = zero slot
#define ZSLOT (TN + 4)
#define WL 7              // Ur/Uz rows per 32-row slice resident in LDS (112 KB total)

__device__ __forceinline__ float sigm(float x) {
  return 1.0f / (1.0f + __expf(-x));
}
__device__ __forceinline__ float tanh_fast(float x) {
  float e = __expf(-2.0f * x);
  return 2.0f / (1.0f + e) - 1.0f;
}

// ---------------- kernel 0: concat weights + biases ----------------
__global__ __launch_bounds__(256) void build_wcat(
    const float* __restrict__ Wr, const float* __restrict__ Wz, const float* __restrict__ Wh,
    const float* __restrict__ br, const float* __restrict__ bz, const float* __restrict__ bh,
    float* __restrict__ wcat, float* __restrict__ bias)
{
  int idx = blockIdx.x * 256 + threadIdx.x;
  if (idx < DN * NC) {
    int k = idx / NC, c = idx % NC;
    float v;
    if (c < 256)      v = Wr[k * UN + c];
    else if (c < 512) v = Wz[k * UN + (c - 256)];
    else              v = Wh[k * UN + (c - 512)];
    wcat[idx] = v;
  }
  if (idx < NC) {
    bias[idx] = (idx < 256) ? br[idx] : ((idx < 512) ? bz[idx - 256] : bh[idx - 512]);
  }
}

// ---------------- kernel 1: P = X @ Wcat + bias  (fp32, LDS-tiled) ----------------
__global__ __launch_bounds__(256) void gemm_xw(
    const float* __restrict__ X, const float* __restrict__ Wc,
    const float* __restrict__ bias, float* __restrict__ P)
{
  __shared__ float As[32][68];
  __shared__ float Bs[32][64];
  const int tid = threadIdx.x;
  const int m0 = blockIdx.x * 64;
  const int n0 = blockIdx.y * 64;
  const int ty = tid >> 4, tx = tid & 15;
  float acc[4][4] = {};

  const int ar = tid >> 3;
  const int ak = (tid & 7) * 4;
  const int bk = tid >> 4;
  const int bn = (tid & 15) * 4;

  for (int k0 = 0; k0 < DN; k0 += 32) {
    float4 a0 = *(const float4*)(X + (size_t)(m0 + ar) * DN + k0 + ak);
    float4 a1 = *(const float4*)(X + (size_t)(m0 + 32 + ar) * DN + k0 + ak);
    As[ak + 0][ar] = a0.x; As[ak + 1][ar] = a0.y; As[ak + 2][ar] = a0.z; As[ak + 3][ar] = a0.w;
    As[ak + 0][32 + ar] = a1.x; As[ak + 1][32 + ar] = a1.y; As[ak + 2][32 + ar] = a1.z; As[ak + 3][32 + ar] = a1.w;
    *(float4*)&Bs[bk][bn]      = *(const float4*)(Wc + (size_t)(k0 + bk) * NC + n0 + bn);
    *(float4*)&Bs[bk + 16][bn] = *(const float4*)(Wc + (size_t)(k0 + bk + 16) * NC + n0 + bn);
    __syncthreads();
#pragma unroll
    for (int kk = 0; kk < 32; kk++) {
      float4 av = *(const float4*)&As[kk][ty * 4];
      float4 bv = *(const float4*)&Bs[kk][tx * 4];
      acc[0][0] += av.x * bv.x; acc[0][1] += av.x * bv.y; acc[0][2] += av.x * bv.z; acc[0][3] += av.x * bv.w;
      acc[1][0] += av.y * bv.x; acc[1][1] += av.y * bv.y; acc[1][2] += av.y * bv.z; acc[1][3] += av.y * bv.w;
      acc[2][0] += av.z * bv.x; acc[2][1] += av.z * bv.y; acc[2][2] += av.z * bv.z; acc[2][3] += av.z * bv.w;
      acc[3][0] += av.w * bv.x; acc[3][1] += av.w * bv.y; acc[3][2] += av.w * bv.z; acc[3][3] += av.w * bv.w;
    }
    __syncthreads();
  }
  float4 bb = *(const float4*)(bias + n0 + tx * 4);
#pragma unroll
  for (int i = 0; i < 4; i++) {
    float4 o;
    o.x = acc[i][0] + bb.x; o.y = acc[i][1] + bb.y;
    o.z = acc[i][2] + bb.z; o.w = acc[i][3] + bb.w;
    *(float4*)(P + (size_t)(m0 + ty * 4 + i) * NC + n0 + tx * 4) = o;
  }
}

// ---------------- kernel 2: the recurrence, one block per batch ----------------
// R9/R11 structure (1628 us) with ONE change in the proven-good category (R8's lever):
// WL 6 -> 7 (stream 416 -> 384 KB/step), made to fit by aliasing ls/lpr/lpz (12 KB, live
// A..A') with redd (16 KB, live D..E) in one pool -- lifetimes are barrier-separated within
// every step. Prologue stages the init vector through hv instead of ls (same values).
// All phases, barriers, global access patterns, and the register recipe are unchanged.
__global__ __launch_bounds__(1024, 4) void recurrent_kernel(
    const float* __restrict__ P,
    const float* __restrict__ Ur, const float* __restrict__ Uz, const float* __restrict__ Uh,
    const int* __restrict__ dep, const int* __restrict__ mask,
    const float* __restrict__ init,
    float* __restrict__ out,
    float* __restrict__ buf_s, float* __restrict__ buf_pr, float* __restrict__ buf_pz)
{
  const int b = blockIdx.x;
  const int tid = threadIdx.x;
  const int g = tid >> 8;
  const int u = tid & 255;
  const int wv = tid >> 6;        // 0..15
  const int mat = wv & 1;         // 0 = Ur, 1 = Uz
  const int s   = wv >> 1;        // 0..7 : 32-row slice
  const int l   = tid & 63;

  // --- Uh in VGPRs: column u, k in [64g, 64g+64) ---
  float wh[64];
  {
    const float* p2 = Uh + (size_t)(64 * g) * UN + u;
#pragma unroll
    for (int kk = 0; kk < 64; kk++) {
      wh[kk] = p2[(size_t)kk * UN];
    }
  }
  const float* Um = mat ? Uz : Ur;

  __shared__ float4 wlds[2][8][WL][64];   // 112 KB LDS-resident weight rows
  __shared__ float upool[4096];           // 16 KB union: {ls,lpr,lpz} (A..A') / redd (D..E)
  float (*ls)[256]  = (float(*)[256])(upool);
  float (*lpr)[256] = (float(*)[256])(upool + 1024);
  float (*lpz)[256] = (float(*)[256])(upool + 2048);
  float (*redd)[8][256] = (float(*)[8][256])(upool);
  __shared__ float lx[NC];
  __shared__ float rs[256], hs[256], zv[256], hv[256];
  __shared__ float red0[4][256];
  __shared__ float scur[256], prcur[256], pzcur[256];
  __shared__ int eff[TN], nxt[TN + 1];
  __shared__ int mloc[TN];
  __shared__ int deploc[TN * 3];

  // stage LDS-resident weight rows: rows 32s..32s+WL-1 of each slice, both matrices
  for (int i = tid; i < 2 * 8 * WL * 64; i += 1024) {
    int mm = i / (8 * WL * 64);
    int r2 = i % (8 * WL * 64);
    int ss = r2 / (WL * 64);
    int rr = (r2 / 64) % WL;
    int ll = i & 63;
    wlds[mm][ss][rr][ll] = ((const float4*)(mm ? Uz : Ur))[(size_t)(32 * ss + rr) * 64 + ll];
  }
  for (int i = tid; i < TN; i += 1024) mloc[i] = mask[b * TN + i];
  for (int i = tid; i < TN * 3; i += 1024) deploc[i] = dep[i];

  const size_t bufBase = (size_t)b * SLOTS * UN;

  // prologue: stage initial states to buf_s, zero slot, current-state LDS
  {
    float v = init[((size_t)g * BN + b) * UN + u];
    buf_s[bufBase + (size_t)(TN + g) * UN + u] = v;
    if (tid < 256) {
      scur[u] = 0.0f; prcur[u] = 0.0f; pzcur[u] = 0.0f;
      buf_s[bufBase + (size_t)ZSLOT * UN + u] = 0.0f;
      buf_pr[bufBase + (size_t)ZSLOT * UN + u] = 0.0f;
      buf_pz[bufBase + (size_t)ZSLOT * UN + u] = 0.0f;
    }
  }
  __syncthreads();

  // eff[] (last active <= t, else ZSLOT) and nxt[] (next active >= t, else TN):
  // pure functions of mask, computed once (visibility covered by prologue barriers)
  if (tid == 0) {
    int e = ZSLOT;
    for (int t2 = 0; t2 < TN; t2++) { if (mloc[t2]) e = t2; eff[t2] = e; }
  } else if (tid == 64) {
    nxt[TN] = TN;
    int e = TN;
    for (int t2 = TN - 1; t2 >= 0; t2--) { if (mloc[t2]) e = t2; nxt[t2] = e; }
  }

  // ---- D-phase projection of a 256-vector through Ur|Uz: WL LDS rows + streamed rows ----
  auto projD = [&](const float* hsrc) {
    const float* hb = hsrc + 32 * s;
    float4 a = {0, 0, 0, 0};
#pragma unroll
    for (int r = 0; r < WL; r++) {
      float hk = hb[r];
      float4 w = wlds[mat][s][r][l];
      a.x = fmaf(hk, w.x, a.x); a.y = fmaf(hk, w.y, a.y);
      a.z = fmaf(hk, w.z, a.z); a.w = fmaf(hk, w.w, a.w);
    }
    const float4* p = (const float4*)Um + (size_t)(32 * s + WL) * 64 + l;
#pragma unroll 4
    for (int r = 0; r < 32 - WL; r++) {
      float hk = hb[WL + r];
      float4 w = p[(size_t)r * 64];
      a.x = fmaf(hk, w.x, a.x); a.y = fmaf(hk, w.y, a.y);
      a.z = fmaf(hk, w.z, a.z); a.w = fmaf(hk, w.w, a.w);
    }
    *(float4*)&redd[mat][s][4 * l] = a;
  };

  // initial-state projections through Ur and Uz (staged via hv; redd aliases ls -- unused here)
#pragma unroll 1
  for (int gg = 0; gg < 4; gg++) {
    if (tid < 256) hv[u] = init[((size_t)gg * BN + b) * UN + u];
    __syncthreads();
    projD(hv);
    __syncthreads();
    if (tid < 256) {
      float prn = 0.0f, pzn = 0.0f;
#pragma unroll
      for (int q = 0; q < 8; q++) { prn += redd[0][q][tid]; pzn += redd[1][q][tid]; }
      buf_pr[bufBase + (size_t)(TN + gg) * UN + tid] = prn;
      buf_pz[bufBase + (size_t)(TN + gg) * UN + tid] = pzn;
    }
    __syncthreads();
  }

  const size_t outB = (size_t)b * TN * UN;
  const size_t pB = (size_t)b * TN * NC;

  // preload lx for the first active step
  {
    int t0 = nxt[0];
    if (t0 < TN && tid < NC) lx[tid] = P[pB + (size_t)t0 * NC + tid];
  }
  __syncthreads();

#pragma unroll 1
  for (int t = 0; t < TN; t++) {
    if (mloc[t] == 0) {
      if (tid < 256) out[outB + (size_t)t * UN + u] = 0.0f;
      continue;                    // eff/nxt precomputed: no barrier, no LDS touch
    }
    // ---- A: gather 4 source states + cached projections ----
    if (t > 0 && g == 0) {
      ls[0][u] = scur[u]; lpr[0][u] = prcur[u]; lpz[0][u] = pzcur[u];
    } else {
      int src = (t == 0) ? (TN + g) : eff[deploc[(t - 1) * 3 + (g - 1)]];
      size_t base = bufBase + (size_t)src * UN + u;
      ls[g][u]  = buf_s[base];
      lpr[g][u] = buf_pr[base];
      lpz[g][u] = buf_pz[base];
    }
    __syncthreads();
    // ---- A': gates (elementwise) ---- (last reader of ls/lpr/lpz)
    if (tid < 256) {
      float s0 = ls[0][u], s1 = ls[1][u], s2 = ls[2][u], s3 = ls[3][u];
      float xr = lx[u];
      float r0 = sigm(xr + lpr[0][u]);
      float r1 = sigm(xr + lpr[1][u]);
      float r2 = sigm(xr + lpr[2][u]);
      float r3 = sigm(xr + lpr[3][u]);
      rs[u] = r0 * s0 + r1 * s1 + r2 * s2 + r3 * s3;
      hs[u] = (s0 + s1) + (s2 + s3);
      zv[u] = sigm(lx[256 + u] + ((lpz[0][u] + lpz[1][u]) + (lpz[2][u] + lpz[3][u])));
    }
    __syncthreads();
    // ---- B: live matvec rs @ Uh (register-resident Uh) ----
    {
      float a0 = 0, a1 = 0, a2 = 0, a3 = 0;
      const float4* v4 = (const float4*)&rs[64 * g];
#pragma unroll
      for (int kk = 0; kk < 16; kk++) {
        float4 v = v4[kk];
        a0 += v.x * wh[4 * kk];     a1 += v.y * wh[4 * kk + 1];
        a2 += v.z * wh[4 * kk + 2]; a3 += v.w * wh[4 * kk + 3];
      }
      red0[g][u] = (a0 + a1) + (a2 + a3);
    }
    __syncthreads();
    // ---- C: h, output ---- (last reader of lx)
    if (tid < 256) {
      float ht = tanh_fast(lx[512 + u] + ((red0[0][u] + red0[1][u]) + (red0[2][u] + red0[3][u])));
      float z = zv[u];
      float h = z * hs[u] * 0.25f + (1.0f - z) * ht;
      hv[u] = h; scur[u] = h;
      out[outB + (size_t)t * UN + u] = h;
    }
    __syncthreads();
    // ---- D: next-lx refill (hides under weight stream) + projections (writes redd) ----
    {
      const int tn = nxt[t + 1];                 // block-uniform
      if (tn < TN && tid < NC) lx[tid] = P[pB + (size_t)tn * NC + tid];
    }
    projD(hv);
    __syncthreads();
    // ---- E: commit state + cached projections ---- (last reader of redd)
    if (tid < 256) {
      float prn = 0.0f, pzn = 0.0f;
#pragma unroll
      for (int q = 0; q < 8; q++) { prn += redd[0][q][tid]; pzn += redd[1][q][tid]; }
      prcur[tid] = prn; pzcur[tid] = pzn;
      size_t base = bufBase + (size_t)t * UN + tid;
      buf_s[base]  = hv[tid];
      buf_pr[base] = prn;
      buf_pz[base] = pzn;
    }
    __syncthreads();
  }

  // epilogue: last_out, last_state
  if (tid < 256) {
    float lst = scur[u];
    out[(size_t)BN * TN * UN + (size_t)b * UN + u] = mloc[TN - 1] ? lst : 0.0f;
    out[(size_t)BN * TN * UN + (size_t)BN * UN + (size_t)b * UN + u] = lst;
  }
}

extern "C" void kernel_launch(void* const* d_in, const int* in_sizes, int n_in,
                              void* d_out, int out_size, void* d_ws, size_t ws_size,
                              hipStream_t stream) {
  const float* inputs       = (const float*)d_in[0];
  const int*   dependencies = (const int*)d_in[1];
  const int*   mask         = (const int*)d_in[2];
  const float* initial      = (const float*)d_in[3];
  const float* Wz = (const float*)d_in[4];
  const float* Wr = (const float*)d_in[5];
  const float* Wh = (const float*)d_in[6];
  const float* Uz = (const float*)d_in[7];
  const float* Ur = (const float*)d_in[8];
  const float* Uh = (const float*)d_in[9];
  const float* bz = (const float*)d_in[10];
  const float* br = (const float*)d_in[11];
  const float* bh = (const float*)d_in[12];

  float* out = (float*)d_out;
  float* ws  = (float*)d_ws;
  float* wcat    = ws;                                   // 256*768
  float* bias    = wcat + (size_t)DN * NC;               // 768
  float* precomp = bias + NC;                            // B*T*768
  float* buf_s   = precomp + (size_t)BN * TN * NC;       // B*SLOTS*256 each
  float* buf_pr  = buf_s + (size_t)BN * SLOTS * UN;
  float* buf_pz  = buf_pr + (size_t)BN * SLOTS * UN;

  build_wcat<<<(DN * NC + 255) / 256, 256, 0, stream>>>(Wr, Wz, Wh, br, bz, bh, wcat, bias);
  gemm_xw<<<dim3(BN * TN / 64, NC / 64), 256, 0, stream>>>(inputs, wcat, bias, precomp);
  recurrent_kernel<<<BN, 1024, 0, stream>>>(precomp, Ur, Uz, Uh, dependencies, mask, initial,
                                            out, buf_s, buf_pr, buf_pz);
}

// Round 13
// 1823.261 us; speedup vs baseline: 1.0208x; 1.0208x over previous
//
#include <hip/hip_runtime.h>
#include <cstdint>
#include <cstddef>

#define BN 64
#define TN 512
#define DN 256
#define UN 256
#define NC 768            // 3*UN, order: r | z | h
#define SLOTS (TN + 5)    // slots TN..TN+3 = initial states, TN+4 = zero slot
#define ZSLOT (TN + 4)
#define WL 6              // Ur/Uz rows per 32-row slice resident in LDS (96 KB total)

#define GBM 128           // gemm tile M
#define GBN 128           // gemm tile N
#define GBK 16            // gemm K-slab
#define APAD 132          // As row stride (2-way store conflicts = free; 16B-aligned reads)

__device__ __forceinline__ float sigm(float x) {
  return 1.0f / (1.0f + __expf(-x));
}
__device__ __forceinline__ float tanh_fast(float x) {
  float e = __expf(-2.0f * x);
  return 2.0f / (1.0f + e) - 1.0f;
}

// ---------------- kernel 0: concat weights + biases ----------------
__global__ __launch_bounds__(256) void build_wcat(
    const float* __restrict__ Wr, const float* __restrict__ Wz, const float* __restrict__ Wh,
    const float* __restrict__ br, const float* __restrict__ bz, const float* __restrict__ bh,
    float* __restrict__ wcat, float* __restrict__ bias)
{
  int idx = blockIdx.x * 256 + threadIdx.x;
  if (idx < DN * NC) {
    int k = idx / NC, c = idx % NC;
    float v;
    if (c < 256)      v = Wr[k * UN + c];
    else if (c < 512) v = Wz[k * UN + (c - 256)];
    else              v = Wh[k * UN + (c - 512)];
    wcat[idx] = v;
  }
  if (idx < NC) {
    bias[idx] = (idx < 256) ? br[idx] : ((idx < 512) ? bz[idx - 256] : bh[idx - 512]);
  }
}

// ---------------- kernel 1: P = X @ Wcat + bias  (fp32, 128x128 tile, double-buffered) ----
// 256 threads; each computes a 2x2 grid of 4x4 sub-blocks (64 acc). Per kk: 64 FMA vs
// 4 ds_read_b128 -> FMA-bound (the old 64x64 tile was LDS-bound at 16 FMA / 2 reads).
#define FMA4(ar_, av_, bv_)                      \
  ar_[0] = fmaf(av_, bv_.x, ar_[0]);             \
  ar_[1] = fmaf(av_, bv_.y, ar_[1]);             \
  ar_[2] = fmaf(av_, bv_.z, ar_[2]);             \
  ar_[3] = fmaf(av_, bv_.w, ar_[3]);

__global__ __launch_bounds__(256) void gemm_xw(
    const float* __restrict__ X, const float* __restrict__ Wc,
    const float* __restrict__ bias, float* __restrict__ P)
{
  __shared__ float As[2][GBK][APAD];   // ~8.3 KB x2
  __shared__ float Bs[2][GBK][GBN];    // 8 KB x2
  const int tid = threadIdx.x;
  const int m0 = blockIdx.x * GBM;
  const int n0 = blockIdx.y * GBN;
  const int tx = tid & 15;             // col group 0..15
  const int ty = tid >> 4;             // row group 0..15

  // staging roles: A tile 128x16 = 512 f4, 2/thread (rows ar, ar+64, k-quad ak);
  //                B tile 16x128 = 512 f4, 2/thread (rows bk, bk+8, col-quad bn)
  const int ar = tid >> 2;             // 0..63
  const int ak = (tid & 3) * 4;        // 0,4,8,12
  const int bk = tid >> 5;             // 0..7
  const int bn = (tid & 31) * 4;       // 0..124

  float acc[2][2][4][4] = {};

  auto stage = [&](int k0, int buf) {
    float4 a0 = *(const float4*)(X + (size_t)(m0 + ar) * DN + k0 + ak);
    float4 a1 = *(const float4*)(X + (size_t)(m0 + 64 + ar) * DN + k0 + ak);
    As[buf][ak + 0][ar] = a0.x; As[buf][ak + 1][ar] = a0.y;
    As[buf][ak + 2][ar] = a0.z; As[buf][ak + 3][ar] = a0.w;
    As[buf][ak + 0][64 + ar] = a1.x; As[buf][ak + 1][64 + ar] = a1.y;
    As[buf][ak + 2][64 + ar] = a1.z; As[buf][ak + 3][64 + ar] = a1.w;
    *(float4*)&Bs[buf][bk][bn]     = *(const float4*)(Wc + (size_t)(k0 + bk) * NC + n0 + bn);
    *(float4*)&Bs[buf][bk + 8][bn] = *(const float4*)(Wc + (size_t)(k0 + bk + 8) * NC + n0 + bn);
  };

  stage(0, 0);
  __syncthreads();
#pragma unroll 1
  for (int kt = 0; kt < DN / GBK; kt++) {
    const int buf = kt & 1;
    if (kt + 1 < DN / GBK) stage((kt + 1) * GBK, buf ^ 1);
#pragma unroll
    for (int kk = 0; kk < GBK; kk++) {
      float4 a0 = *(const float4*)&As[buf][kk][ty * 4];
      float4 a1 = *(const float4*)&As[buf][kk][64 + ty * 4];
      float4 b0 = *(const float4*)&Bs[buf][kk][tx * 4];
      float4 b1 = *(const float4*)&Bs[buf][kk][64 + tx * 4];
      FMA4(acc[0][0][0], a0.x, b0); FMA4(acc[0][0][1], a0.y, b0);
      FMA4(acc[0][0][2], a0.z, b0); FMA4(acc[0][0][3], a0.w, b0);
      FMA4(acc[0][1][0], a0.x, b1); FMA4(acc[0][1][1], a0.y, b1);
      FMA4(acc[0][1][2], a0.z, b1); FMA4(acc[0][1][3], a0.w, b1);
      FMA4(acc[1][0][0], a1.x, b0); FMA4(acc[1][0][1], a1.y, b0);
      FMA4(acc[1][0][2], a1.z, b0); FMA4(acc[1][0][3], a1.w, b0);
      FMA4(acc[1][1][0], a1.x, b1); FMA4(acc[1][1][1], a1.y, b1);
      FMA4(acc[1][1][2], a1.z, b1); FMA4(acc[1][1][3], a1.w, b1);
    }
    __syncthreads();
  }

  float4 bb0 = *(const float4*)(bias + n0 + tx * 4);
  float4 bb1 = *(const float4*)(bias + n0 + 64 + tx * 4);
#pragma unroll
  for (int mi = 0; mi < 2; mi++) {
#pragma unroll
    for (int i = 0; i < 4; i++) {
      const size_t row = (size_t)(m0 + mi * 64 + ty * 4 + i) * NC + n0;
      float4 o0, o1;
      o0.x = acc[mi][0][i][0] + bb0.x; o0.y = acc[mi][0][i][1] + bb0.y;
      o0.z = acc[mi][0][i][2] + bb0.z; o0.w = acc[mi][0][i][3] + bb0.w;
      o1.x = acc[mi][1][i][0] + bb1.x; o1.y = acc[mi][1][i][1] + bb1.y;
      o1.z = acc[mi][1][i][2] + bb1.z; o1.w = acc[mi][1][i][3] + bb1.w;
      *(float4*)(P + row + tx * 4) = o0;
      *(float4*)(P + row + 64 + tx * 4) = o1;
    }
  }
}

// ---------------- kernel 2: the recurrence, one block per batch ----------------
// == R11 verbatim (best measured: 1622/1628 us). R8 structure + two surgical latency edits:
//  (1) eff[]/nxt[] precomputed from mask; masked steps are barrier-free (out-zero + continue).
//  (2) next active step's x-row loaded global->LDS inside phase D (lx is dead there).
// Measured dead ends (do not revisit): fp16 weights (absmax 0.072); cross-CU split (+8us/sync);
// producer/consumer waves (spill + L2 thrash); gather moved into D (+7.4MB HBM writeback);
// WL=7 via LDS aliasing (null -- stream no longer binding at 416 KB/step).
__global__ __launch_bounds__(1024, 4) void recurrent_kernel(
    const float* __restrict__ P,
    const float* __restrict__ Ur, const float* __restrict__ Uz, const float* __restrict__ Uh,
    const int* __restrict__ dep, const int* __restrict__ mask,
    const float* __restrict__ init,
    float* __restrict__ out,
    float* __restrict__ buf_s, float* __restrict__ buf_pr, float* __restrict__ buf_pz)
{
  const int b = blockIdx.x;
  const int tid = threadIdx.x;
  const int g = tid >> 8;
  const int u = tid & 255;
  const int wv = tid >> 6;        // 0..15
  const int mat = wv & 1;         // 0 = Ur, 1 = Uz
  const int s   = wv >> 1;        // 0..7 : 32-row slice
  const int l   = tid & 63;

  // --- Uh in VGPRs: column u, k in [64g, 64g+64) ---
  float wh[64];
  {
    const float* p2 = Uh + (size_t)(64 * g) * UN + u;
#pragma unroll
    for (int kk = 0; kk < 64; kk++) {
      wh[kk] = p2[(size_t)kk * UN];
    }
  }
  const float* Um = mat ? Uz : Ur;

  __shared__ float4 wlds[2][8][WL][64];   // 96 KB LDS-resident weight rows
  __shared__ float ls[4][256], lpr[4][256], lpz[4][256];
  __shared__ float lx[NC];
  __shared__ float rs[256], hs[256], zv[256], hv[256];
  __shared__ float red0[4][256];
  __shared__ float redd[2][8][256];       // 16 KB
  __shared__ float scur[256], prcur[256], pzcur[256];
  __shared__ int eff[TN], nxt[TN + 1];
  __shared__ int mloc[TN];
  __shared__ int deploc[TN * 3];

  // stage LDS-resident weight rows: rows 32s..32s+WL-1 of each slice, both matrices
  for (int i = tid; i < 2 * 8 * WL * 64; i += 1024) {
    int mm = i / (8 * WL * 64);
    int r2 = i % (8 * WL * 64);
    int ss = r2 / (WL * 64);
    int rr = (r2 / 64) % WL;
    int ll = i & 63;
    wlds[mm][ss][rr][ll] = ((const float4*)(mm ? Uz : Ur))[(size_t)(32 * ss + rr) * 64 + ll];
  }
  for (int i = tid; i < TN; i += 1024) mloc[i] = mask[b * TN + i];
  for (int i = tid; i < TN * 3; i += 1024) deploc[i] = dep[i];

  const size_t bufBase = (size_t)b * SLOTS * UN;

  // prologue: stage initial states, zero slot, current-state LDS
  {
    float v = init[((size_t)g * BN + b) * UN + u];
    ls[g][u] = v;
    buf_s[bufBase + (size_t)(TN + g) * UN + u] = v;
    if (tid < 256) {
      scur[u] = 0.0f; prcur[u] = 0.0f; pzcur[u] = 0.0f;
      buf_s[bufBase + (size_t)ZSLOT * UN + u] = 0.0f;
      buf_pr[bufBase + (size_t)ZSLOT * UN + u] = 0.0f;
      buf_pz[bufBase + (size_t)ZSLOT * UN + u] = 0.0f;
    }
  }
  __syncthreads();

  // eff[] (last active <= t, else ZSLOT) and nxt[] (next active >= t, else TN):
  // pure functions of mask, computed once (visibility covered by prologue barriers)
  if (tid == 0) {
    int e = ZSLOT;
    for (int t2 = 0; t2 < TN; t2++) { if (mloc[t2]) e = t2; eff[t2] = e; }
  } else if (tid == 64) {
    nxt[TN] = TN;
    int e = TN;
    for (int t2 = TN - 1; t2 >= 0; t2--) { if (mloc[t2]) e = t2; nxt[t2] = e; }
  }

  // ---- D-phase projection of a 256-vector through Ur|Uz: WL LDS rows + streamed rows ----
  auto projD = [&](const float* hsrc) {
    const float* hb = hsrc + 32 * s;
    float4 a = {0, 0, 0, 0};
#pragma unroll
    for (int r = 0; r < WL; r++) {
      float hk = hb[r];
      float4 w = wlds[mat][s][r][l];
      a.x = fmaf(hk, w.x, a.x); a.y = fmaf(hk, w.y, a.y);
      a.z = fmaf(hk, w.z, a.z); a.w = fmaf(hk, w.w, a.w);
    }
    const float4* p = (const float4*)Um + (size_t)(32 * s + WL) * 64 + l;
#pragma unroll 4
    for (int r = 0; r < 32 - WL; r++) {
      float hk = hb[WL + r];
      float4 w = p[(size_t)r * 64];
      a.x = fmaf(hk, w.x, a.x); a.y = fmaf(hk, w.y, a.y);
      a.z = fmaf(hk, w.z, a.z); a.w = fmaf(hk, w.w, a.w);
    }
    *(float4*)&redd[mat][s][4 * l] = a;
  };

  // initial-state projections through Ur and Uz
#pragma unroll 1
  for (int gg = 0; gg < 4; gg++) {
    projD(&ls[gg][0]);
    __syncthreads();
    if (tid < 256) {
      float prn = 0.0f, pzn = 0.0f;
#pragma unroll
      for (int q = 0; q < 8; q++) { prn += redd[0][q][tid]; pzn += redd[1][q][tid]; }
      buf_pr[bufBase + (size_t)(TN + gg) * UN + tid] = prn;
      buf_pz[bufBase + (size_t)(TN + gg) * UN + tid] = pzn;
    }
    __syncthreads();
  }

  const size_t outB = (size_t)b * TN * UN;
  const size_t pB = (size_t)b * TN * NC;

  // preload lx for the first active step
  {
    int t0 = nxt[0];
    if (t0 < TN && tid < NC) lx[tid] = P[pB + (size_t)t0 * NC + tid];
  }
  __syncthreads();

#pragma unroll 1
  for (int t = 0; t < TN; t++) {
    if (mloc[t] == 0) {
      if (tid < 256) out[outB + (size_t)t * UN + u] = 0.0f;
      continue;                    // eff/nxt precomputed: no barrier, no LDS touch
    }
    // ---- A: gather 4 source states + cached projections ----
    if (t > 0 && g == 0) {
      ls[0][u] = scur[u]; lpr[0][u] = prcur[u]; lpz[0][u] = pzcur[u];
    } else {
      int src = (t == 0) ? (TN + g) : eff[deploc[(t - 1) * 3 + (g - 1)]];
      size_t base = bufBase + (size_t)src * UN + u;
      ls[g][u]  = buf_s[base];
      lpr[g][u] = buf_pr[base];
      lpz[g][u] = buf_pz[base];
    }
    __syncthreads();
    // ---- A': gates (elementwise) ----
    if (tid < 256) {
      float s0 = ls[0][u], s1 = ls[1][u], s2 = ls[2][u], s3 = ls[3][u];
      float xr = lx[u];
      float r0 = sigm(xr + lpr[0][u]);
      float r1 = sigm(xr + lpr[1][u]);
      float r2 = sigm(xr + lpr[2][u]);
      float r3 = sigm(xr + lpr[3][u]);
      rs[u] = r0 * s0 + r1 * s1 + r2 * s2 + r3 * s3;
      hs[u] = (s0 + s1) + (s2 + s3);
      zv[u] = sigm(lx[256 + u] + ((lpz[0][u] + lpz[1][u]) + (lpz[2][u] + lpz[3][u])));
    }
    __syncthreads();
    // ---- B: live matvec rs @ Uh (register-resident Uh) ----
    {
      float a0 = 0, a1 = 0, a2 = 0, a3 = 0;
      const float4* v4 = (const float4*)&rs[64 * g];
#pragma unroll
      for (int kk = 0; kk < 16; kk++) {
        float4 v = v4[kk];
        a0 += v.x * wh[4 * kk];     a1 += v.y * wh[4 * kk + 1];
        a2 += v.z * wh[4 * kk + 2]; a3 += v.w * wh[4 * kk + 3];
      }
      red0[g][u] = (a0 + a1) + (a2 + a3);
    }
    __syncthreads();
    // ---- C: h, output ---- (last reader of lx)
    if (tid < 256) {
      float ht = tanh_fast(lx[512 + u] + ((red0[0][u] + red0[1][u]) + (red0[2][u] + red0[3][u])));
      float z = zv[u];
      float h = z * hs[u] * 0.25f + (1.0f - z) * ht;
      hv[u] = h; scur[u] = h;
      out[outB + (size_t)t * UN + u] = h;
    }
    __syncthreads();
    // ---- D: next-lx refill (oldest VMEM op; hides under weight stream) + projections ----
    {
      const int tn = nxt[t + 1];                 // block-uniform
      if (tn < TN && tid < NC) lx[tid] = P[pB + (size_t)tn * NC + tid];
    }
    projD(hv);
    __syncthreads();
    // ---- E: commit state + cached projections ----
    if (tid < 256) {
      float prn = 0.0f, pzn = 0.0f;
#pragma unroll
      for (int q = 0; q < 8; q++) { prn += redd[0][q][tid]; pzn += redd[1][q][tid]; }
      prcur[tid] = prn; pzcur[tid] = pzn;
      size_t base = bufBase + (size_t)t * UN + tid;
      buf_s[base]  = hv[tid];
      buf_pr[base] = prn;
      buf_pz[base] = pzn;
    }
    __syncthreads();
  }

  // epilogue: last_out, last_state
  if (tid < 256) {
    float lst = scur[u];
    out[(size_t)BN * TN * UN + (size_t)b * UN + u] = mloc[TN - 1] ? lst : 0.0f;
    out[(size_t)BN * TN * UN + (size_t)BN * UN + (size_t)b * UN + u] = lst;
  }
}

extern "C" void kernel_launch(void* const* d_in, const int* in_sizes, int n_in,
                              void* d_out, int out_size, void* d_ws, size_t ws_size,
                              hipStream_t stream) {
  const float* inputs       = (const float*)d_in[0];
  const int*   dependencies = (const int*)d_in[1];
  const int*   mask         = (const int*)d_in[2];
  const float* initial      = (const float*)d_in[3];
  const float* Wz = (const float*)d_in[4];
  const float* Wr = (const float*)d_in[5];
  const float* Wh = (const float*)d_in[6];
  const float* Uz = (const float*)d_in[7];
  const float* Ur = (const float*)d_in[8];
  const float* Uh = (const float*)d_in[9];
  const float* bz = (const float*)d_in[10];
  const float* br = (const float*)d_in[11];
  const float* bh = (const float*)d_in[12];

  float* out = (float*)d_out;
  float* ws  = (float*)d_ws;
  float* wcat    = ws;                                   // 256*768
  float* bias    = wcat + (size_t)DN * NC;               // 768
  float* precomp = bias + NC;                            // B*T*768
  float* buf_s   = precomp + (size_t)BN * TN * NC;       // B*SLOTS*256 each
  float* buf_pr  = buf_s + (size_t)BN * SLOTS * UN;
  float* buf_pz  = buf_pr + (size_t)BN * SLOTS * UN;

  build_wcat<<<(DN * NC + 255) / 256, 256, 0, stream>>>(Wr, Wz, Wh, br, bz, bh, wcat, bias);
  gemm_xw<<<dim3(BN * TN / GBM, NC / GBN), 256, 0, stream>>>(inputs, wcat, bias, precomp);
  recurrent_kernel<<<BN, 1024, 0, stream>>>(precomp, Ur, Uz, Uh, dependencies, mask, initial,
                                            out, buf_s, buf_pr, buf_pz);
}